// Round 7
// baseline (714.379 us; speedup 1.0000x reference)
//
#include <hip/hip_runtime.h>
#include <hip/hip_bf16.h>
#include <stdint.h>

#define L_ 25
#define E_ 64
#define B_ 1000
#define S_ 512
#define NCELL L_                  // 25 cells/block (1 batch elem, all layers)
#define TPBR (NCELL * 16)         // 400 threads; thread = (layer, half, j)
#define NSUPER (S_ / 2 + L_ - 1)  // 280 supersteps (2 timesteps each)
#define XG 20                     // per-cell xbuf stride (words)

typedef float v4f __attribute__((ext_vector_type(4)));

struct Args {
  const void *x, *emb;
  const void *Wxz0, *Whz0, *bz0, *Wxr0, *Whr0, *br0, *WxH0, *WrH0, *bH0;
  const void *Wxz, *Whz, *bz, *Wxr, *Whr, *br, *WxH, *WrH, *bH, *Why, *by;
  void* out;
  const int* flag;
  void* pre;
};

__device__ __forceinline__ float ulo(uint32_t u) { return __uint_as_float(u << 16); }
__device__ __forceinline__ float uhi(uint32_t u) { return __uint_as_float(u & 0xffff0000u); }
__device__ __forceinline__ float toF(float v) { return v; }
__device__ __forceinline__ float toF(__hip_bfloat16 v) { return __bfloat162float(v); }
__device__ __forceinline__ void stP(float* p, float v) { *p = v; }
__device__ __forceinline__ void stP(__hip_bfloat16* p, float v) { *p = __float2bfloat16(v); }

__device__ __forceinline__ void loadrow(const float* p, v4f& a, v4f& b) {
  a = ((const v4f*)p)[0];
  b = ((const v4f*)p)[1];
}
__device__ __forceinline__ void loadrow(const __hip_bfloat16* p, v4f& a, v4f& b) {
  const uint4 v = *(const uint4*)p;
  a = (v4f){ulo(v.x), uhi(v.x), ulo(v.y), uhi(v.y)};
  b = (v4f){ulo(v.z), uhi(v.z), ulo(v.w), uhi(v.w)};
}

// ---- cross-lane XOR exchange, pure VALU DPP (16-lane rows) ----
template <int C>
__device__ __forceinline__ float dpp(float v) {
  return __int_as_float(__builtin_amdgcn_mov_dpp(__float_as_int(v), C, 0xF, 0xF, true));
}
__device__ __forceinline__ float xor4f(float v) { return dpp<0x1B>(dpp<0x141>(v)); }  // half_mirror(^7) o quad_perm(^3) = ^4
__device__ __forceinline__ float xor8f(float v) { return dpp<0x128>(v); }             // row_ror:8 = ^8 in 16-lane row

__device__ __forceinline__ float sigmo_(float x) {
  // exp overflow -> inf -> rcp -> 0: graceful, no clamp needed
  return __builtin_amdgcn_rcpf(1.f + __expf(-x));
}
__device__ __forceinline__ float tanh_(float x) {
  x = fmaxf(x, -15.f);  // avoid inf*0 NaN on the negative side
  const float e = __expf(-2.f * x);
  return (1.f - e) * __builtin_amdgcn_rcpf(1.f + e);
}

// One GRU cell update on a 16-lane cell. azp/arp/ahp hold this half's partial
// (bias and x-part pre-halved/split); weights: element m = row (j^(4hf+m)).
__device__ __forceinline__ float cellstep16(float hown, float azp, float arp, float ahp,
                                            v4f whz, v4f whr, v4f wrh, bool hfb) {
  const float x4 = xor4f(hown);
  const float v0 = hfb ? x4 : hown;
  const float v1 = dpp<0xB1>(v0), v2 = dpp<0x4E>(v0), v3 = dpp<0x1B>(v0);
  azp = fmaf(v0, whz[0], azp); arp = fmaf(v0, whr[0], arp);
  azp = fmaf(v1, whz[1], azp); arp = fmaf(v1, whr[1], arp);
  azp = fmaf(v2, whz[2], azp); arp = fmaf(v2, whr[2], arp);
  azp = fmaf(v3, whz[3], azp); arp = fmaf(v3, whr[3], arp);
  const float az = azp + xor8f(azp);  // combine halves -> full sum in all lanes
  const float ar = arp + xor8f(arp);
  const float z = sigmo_(az);
  const float r = sigmo_(ar);
  const float hr = hown * r;
  const float y4 = xor4f(hr);
  const float u0 = hfb ? y4 : hr;
  const float u1 = dpp<0xB1>(u0), u2 = dpp<0x4E>(u0), u3 = dpp<0x1B>(u0);
  ahp = fmaf(u0, wrh[0], ahp);
  ahp = fmaf(u1, wrh[1], ahp);
  ahp = fmaf(u2, wrh[2], ahp);
  ahp = fmaf(u3, wrh[3], ahp);
  const float ah = ahp + xor8f(ahp);
  return fmaf(z, tanh_(ah) - hown, hown);
}

// ---------------------------------------------------------------------------
// Kernel 0: dtype probe (fp32 vs bf16 inputs).
// ---------------------------------------------------------------------------
__global__ void gru_detect(const unsigned short* __restrict__ u16, int* __restrict__ flag) {
  const int i = threadIdx.x;  // 64 threads
  float m = 0.f;
#pragma unroll
  for (int k = 0; k < 4; ++k) {
    const uint32_t u = u16[i * 4 + k];
    float v = fabsf(__uint_as_float(u << 16));
    if (!(v < 1e30f)) v = 1e30f;
    m = fmaxf(m, v);
  }
#pragma unroll
  for (int off = 32; off; off >>= 1) m = fmaxf(m, __shfl_down(m, off, 64));
  if (i == 0) *flag = (m > 2.0f) ? 0 : 1;  // 0 = fp32 inputs, 1 = bf16 inputs
}

// ---------------------------------------------------------------------------
// Kernel 1: layer-0 x-projections, stored PRE-HALVED (x 0.5) so both cell
// halves can add them. Layout: pre[(b*S+t)*24 + j*3 + gate].
// ---------------------------------------------------------------------------
#define DECLP(p) v4f Za##p = {0,0,0,0}, Zb##p = {0,0,0,0}, Ra##p = {0,0,0,0}, \
                     Rb##p = {0,0,0,0}, Ha##p = {0,0,0,0}, Hb##p = {0,0,0,0}
#define FMAP(p, e) { Za##p += (e) * za; Zb##p += (e) * zb; Ra##p += (e) * ra; \
                     Rb##p += (e) * rb; Ha##p += (e) * ha; Hb##p += (e) * hb; }
#define STOREP(p, pos) { PT* o = pre + (size_t)(pos) * 24;                         \
    stP(o+0,  .5f*Za##p[0]); stP(o+1,  .5f*Ra##p[0]); stP(o+2,  .5f*Ha##p[0]);     \
    stP(o+3,  .5f*Za##p[1]); stP(o+4,  .5f*Ra##p[1]); stP(o+5,  .5f*Ha##p[1]);     \
    stP(o+6,  .5f*Za##p[2]); stP(o+7,  .5f*Ra##p[2]); stP(o+8,  .5f*Ha##p[2]);     \
    stP(o+9,  .5f*Za##p[3]); stP(o+10, .5f*Ra##p[3]); stP(o+11, .5f*Ha##p[3]);     \
    stP(o+12, .5f*Zb##p[0]); stP(o+13, .5f*Rb##p[0]); stP(o+14, .5f*Hb##p[0]);     \
    stP(o+15, .5f*Zb##p[1]); stP(o+16, .5f*Rb##p[1]); stP(o+17, .5f*Hb##p[1]);     \
    stP(o+18, .5f*Zb##p[2]); stP(o+19, .5f*Rb##p[2]); stP(o+20, .5f*Hb##p[2]);     \
    stP(o+21, .5f*Zb##p[3]); stP(o+22, .5f*Rb##p[3]); stP(o+23, .5f*Hb##p[3]); }

template <typename T, typename PT>
__device__ void pre_body(const Args& a) {
  const int* x = (const int*)a.x;
  const T* emb = (const T*)a.emb;
  const T* Wz = (const T*)a.Wxz0;
  const T* Wr = (const T*)a.Wxr0;
  const T* Wh = (const T*)a.WxH0;
  PT* pre = (PT*)a.pre;

  const int pos0 = (blockIdx.x * 256 + threadIdx.x) * 4;  // 4 tokens/thread
  const int4 t4 = *(const int4*)(x + pos0);

  DECLP(0); DECLP(1); DECLP(2); DECLP(3);

  for (int kb = 0; kb < 8; ++kb) {
    v4f eA0, eB0, eA1, eB1, eA2, eB2, eA3, eB3;
    loadrow(emb + (size_t)t4.x * E_ + kb * 8, eA0, eB0);
    loadrow(emb + (size_t)t4.y * E_ + kb * 8, eA1, eB1);
    loadrow(emb + (size_t)t4.z * E_ + kb * 8, eA2, eB2);
    loadrow(emb + (size_t)t4.w * E_ + kb * 8, eA3, eB3);
#pragma unroll
    for (int k8 = 0; k8 < 8; ++k8) {
      v4f za, zb, ra, rb, ha, hb;
      const int row = (kb * 8 + k8) * 8;  // wave-uniform
      loadrow(Wz + row, za, zb);
      loadrow(Wr + row, ra, rb);
      loadrow(Wh + row, ha, hb);
      const float e0 = (k8 < 4) ? eA0[k8 & 3] : eB0[k8 & 3];
      const float e1 = (k8 < 4) ? eA1[k8 & 3] : eB1[k8 & 3];
      const float e2 = (k8 < 4) ? eA2[k8 & 3] : eB2[k8 & 3];
      const float e3 = (k8 < 4) ? eA3[k8 & 3] : eB3[k8 & 3];
      FMAP(0, e0); FMAP(1, e1); FMAP(2, e2); FMAP(3, e3);
    }
  }
  STOREP(0, pos0 + 0); STOREP(1, pos0 + 1);
  STOREP(2, pos0 + 2); STOREP(3, pos0 + 3);
}

template <typename PT>
__global__ __launch_bounds__(256, 2) void gru_pre_k(Args a) {
  if (*a.flag == 0) pre_body<float, PT>(a);
  else pre_body<__hip_bfloat16, PT>(a);
}

// ---------------------------------------------------------------------------
// Kernel 2: pipelined recurrence. 16 lanes per cell: lane = hf*8 + j; half hf
// owns k in {4hf..4hf+3}. All h exchange via DPP; LDS only for the inter-layer
// x handoff. Biases & layer-0 pre are pre-halved (both halves add them).
// ---------------------------------------------------------------------------
template <typename T, typename PT>
__device__ void rec_body(const Args& a, float* xbuf) {
  const PT* pre = (const PT*)a.pre;
  const T* Whz0 = (const T*)a.Whz0; const T* bz0 = (const T*)a.bz0;
  const T* Whr0 = (const T*)a.Whr0; const T* br0 = (const T*)a.br0;
  const T* WrH0 = (const T*)a.WrH0; const T* bH0 = (const T*)a.bH0;
  const T* Wxz = (const T*)a.Wxz; const T* Whz = (const T*)a.Whz;
  const T* bz = (const T*)a.bz; const T* Wxr = (const T*)a.Wxr;
  const T* Whr = (const T*)a.Whr; const T* br = (const T*)a.br;
  const T* WxH = (const T*)a.WxH; const T* WrH = (const T*)a.WrH;
  const T* bH = (const T*)a.bH; const T* Why = (const T*)a.Why;
  const T* by = (const T*)a.by;
  T* out = (T*)a.out;

  const int tid = threadIdx.x;
  const int cell = tid >> 4;      // == layer l (1 batch elem per block)
  const int hf = (tid >> 3) & 1;
  const int j = tid & 7;
  const int l = cell;
  const int b = blockIdx.x;
  const bool hfb = (hf != 0);

  // ---- weights as v4f SSA values (27 floats + biases, no arrays) ----
  v4f wxz = {0, 0, 0, 0}, wxr = {0, 0, 0, 0}, wxh = {0, 0, 0, 0};
  v4f whz, whr, wrh, vb;
  if (l == 0) {
#pragma unroll
    for (int m = 0; m < 4; ++m) {
      const int rk = (j ^ (4 * hf + m)) * 8 + j;
      whz[m] = toF(Whz0[rk]); whr[m] = toF(Whr0[rk]); wrh[m] = toF(WrH0[rk]);
    }
    vb = (v4f){0.5f * toF(bz0[j]), 0.5f * toF(br0[j]), 0.5f * toF(bH0[j]), 0.f};
  } else {
    const int base = (l - 1) * 64;
#pragma unroll
    for (int m = 0; m < 4; ++m) {
      const int km = 4 * hf + m;
      const int nk = base + km * 8 + j;
      const int rk = base + (j ^ km) * 8 + j;
      wxz[m] = toF(Wxz[nk]); wxr[m] = toF(Wxr[nk]); wxh[m] = toF(WxH[nk]);
      whz[m] = toF(Whz[rk]); whr[m] = toF(Whr[rk]); wrh[m] = toF(WrH[rk]);
    }
    vb = (v4f){0.5f * toF(bz[(l - 1) * 8 + j]), 0.5f * toF(br[(l - 1) * 8 + j]),
               0.5f * toF(bH[(l - 1) * 8 + j]), 0.f};
  }

  // layer-0 precomputed x-projection (pre-halved; both halves add)
  const PT* ppr = pre + (size_t)b * (S_ * 24) + j * 3;
  float cz0 = 0.f, cr0 = 0.f, ch0 = 0.f, cz1 = 0.f, cr1 = 0.f, ch1 = 0.f;
  if (l == 0) {
    cz0 = toF(ppr[0]);  cr0 = toF(ppr[1]);  ch0 = toF(ppr[2]);
    cz1 = toF(ppr[24]); cr1 = toF(ppr[25]); ch1 = toF(ppr[26]);
  }

  const int gp = (cell > 0) ? (cell - 1) * XG : 0;
  const float* xpe = xbuf + NCELL * XG + gp + hf * 4;  // read when s even
  const float* xpo = xbuf + gp + hf * 4;               // read when s odd
  float* xce = xbuf + cell * XG;                       // write when s even
  float* xco = xbuf + NCELL * XG + cell * XG;          // write when s odd

  float hown = 0.f;  // h[j], replicated in both halves
  __syncthreads();

  for (int s = 0; s < NSUPER; ++s) {
    asm volatile("" : "+v"(wxz), "+v"(wxr), "+v"(wxh), "+v"(whz), "+v"(whr),
                      "+v"(wrh), "+v"(vb));
    const unsigned rel = (unsigned)(s - l);
    if (rel < (unsigned)(S_ / 2)) {
      const float* xp = (s & 1) ? xpo : xpe;
      float* xc = (s & 1) ? xco : xce;
      float az0 = vb[0], ar0 = vb[1], ah0 = vb[2];
      float az1 = vb[0], ar1 = vb[1], ah1 = vb[2];
      if (l == 0) {
        az0 += cz0; ar0 += cr0; ah0 += ch0;
        az1 += cz1; ar1 += cr1; ah1 += ch1;
        if (rel + 1 < (unsigned)(S_ / 2)) {  // prefetch next superstep
          const PT* pn = ppr + (size_t)(rel + 1) * 48;
          cz0 = toF(pn[0]);  cr0 = toF(pn[1]);  ch0 = toF(pn[2]);
          cz1 = toF(pn[24]); cr1 = toF(pn[25]); ch1 = toF(pn[26]);
        }
      } else {
        const v4f x0 = *(const v4f*)(xp);      // slot0, my k-half (broadcast)
        const v4f x1 = *(const v4f*)(xp + 8);  // slot1, my k-half
        az0 = fmaf(x0[0], wxz[0], az0); ar0 = fmaf(x0[0], wxr[0], ar0); ah0 = fmaf(x0[0], wxh[0], ah0);
        az0 = fmaf(x0[1], wxz[1], az0); ar0 = fmaf(x0[1], wxr[1], ar0); ah0 = fmaf(x0[1], wxh[1], ah0);
        az0 = fmaf(x0[2], wxz[2], az0); ar0 = fmaf(x0[2], wxr[2], ar0); ah0 = fmaf(x0[2], wxh[2], ah0);
        az0 = fmaf(x0[3], wxz[3], az0); ar0 = fmaf(x0[3], wxr[3], ar0); ah0 = fmaf(x0[3], wxh[3], ah0);
        az1 = fmaf(x1[0], wxz[0], az1); ar1 = fmaf(x1[0], wxr[0], ar1); ah1 = fmaf(x1[0], wxh[0], ah1);
        az1 = fmaf(x1[1], wxz[1], az1); ar1 = fmaf(x1[1], wxr[1], ar1); ah1 = fmaf(x1[1], wxh[1], ah1);
        az1 = fmaf(x1[2], wxz[2], az1); ar1 = fmaf(x1[2], wxr[2], ar1); ah1 = fmaf(x1[2], wxh[2], ah1);
        az1 = fmaf(x1[3], wxz[3], az1); ar1 = fmaf(x1[3], wxr[3], ar1); ah1 = fmaf(x1[3], wxh[3], ah1);
      }
      const float hn0 = cellstep16(hown, az0, ar0, ah0, whz, whr, wrh, hfb);
      const float hn1 = cellstep16(hn0, az1, ar1, ah1, whz, whr, wrh, hfb);
      // both halves write identical values (same addr, same data: benign dup)
      xc[j] = hn0;
      xc[8 + j] = hn1;
      hown = hn1;
    }
    __syncthreads();
  }

  // ---- epilogue: h_last (dup-write benign) and logits ----
  stP(out + B_ + (l * B_ + b) * 8 + j, hown);
  if (l == L_ - 1) {
    float sum = hown * toF(Why[j]);
    sum += dpp<0xB1>(sum);
    sum += dpp<0x4E>(sum);
    sum += xor4f(sum);
    if (j == 0) stP(out + b, sum + toF(by[0]));  // hf=0/1 write same value
  }
}

template <typename PT>
__global__ __launch_bounds__(TPBR, 6) void gru_rec_k(Args a) {
  __shared__ __align__(16) float xbuf[2 * NCELL * XG];
  if (*a.flag == 0) rec_body<float, PT>(a, xbuf);
  else rec_body<__hip_bfloat16, PT>(a, xbuf);
}

// ---------------------------------------------------------------------------
extern "C" void kernel_launch(void* const* d_in, const int* in_sizes, int n_in,
                              void* d_out, int out_size, void* d_ws, size_t ws_size,
                              hipStream_t stream) {
  Args a;
  a.x = d_in[0];  a.emb = d_in[1];
  a.Wxz0 = d_in[2]; a.Whz0 = d_in[3]; a.bz0 = d_in[4];
  a.Wxr0 = d_in[5]; a.Whr0 = d_in[6]; a.br0 = d_in[7];
  a.WxH0 = d_in[8]; a.WrH0 = d_in[9]; a.bH0 = d_in[10];
  a.Wxz = d_in[11]; a.Whz = d_in[12]; a.bz = d_in[13];
  a.Wxr = d_in[14]; a.Whr = d_in[15]; a.br = d_in[16];
  a.WxH = d_in[17]; a.WrH = d_in[18]; a.bH = d_in[19];
  a.Why = d_in[20]; a.by = d_in[21];
  a.out = d_out;
  a.flag = (const int*)d_ws;
  a.pre = (char*)d_ws + 256;

  gru_detect<<<1, 64, 0, stream>>>((const unsigned short*)d_in[1], (int*)d_ws);

  const size_t needF = (size_t)B_ * S_ * 24 * sizeof(float) + 256;
  const int preGrid = B_ * S_ / 4 / 256;  // 500
  if (ws_size >= needF) {
    gru_pre_k<float><<<preGrid, 256, 0, stream>>>(a);
    gru_rec_k<float><<<B_, TPBR, 0, stream>>>(a);
  } else {  // small workspace: bf16 pre buffer
    gru_pre_k<__hip_bfloat16><<<preGrid, 256, 0, stream>>>(a);
    gru_rec_k<__hip_bfloat16><<<B_, TPBR, 0, stream>>>(a);
  }
}

// Round 8
// 605.378 us; speedup vs baseline: 1.1801x; 1.1801x over previous
//
#include <hip/hip_runtime.h>
#include <hip/hip_bf16.h>
#include <stdint.h>

#define L_ 25
#define E_ 64
#define B_ 1000
#define S_ 512
#define NCELL L_                  // 25 cells/block (1 batch elem, all layers)
#define TPBR (NCELL * 16)         // 400 threads; thread = (layer, half, j)
#define NSUPER (S_ / 2 + L_ - 1)  // 280 supersteps (2 timesteps each)
#define XG 20                     // per-cell xbuf stride (words)

#define KZR 1.44269504088896f     // log2(e): folded into z/r weights
#define KH 2.88539008177793f      // 2*log2(e): folded into H-gate weights

typedef float v4f __attribute__((ext_vector_type(4)));
typedef float v2f __attribute__((ext_vector_type(2)));

struct Args {
  const void *x, *emb;
  const void *Wxz0, *Whz0, *bz0, *Wxr0, *Whr0, *br0, *WxH0, *WrH0, *bH0;
  const void *Wxz, *Whz, *bz, *Wxr, *Whr, *br, *WxH, *WrH, *bH, *Why, *by;
  void* out;
  const int* flag;
  void* pre;
};

__device__ __forceinline__ float ulo(uint32_t u) { return __uint_as_float(u << 16); }
__device__ __forceinline__ float uhi(uint32_t u) { return __uint_as_float(u & 0xffff0000u); }
__device__ __forceinline__ float toF(float v) { return v; }
__device__ __forceinline__ float toF(__hip_bfloat16 v) { return __bfloat162float(v); }
__device__ __forceinline__ void stP(float* p, float v) { *p = v; }
__device__ __forceinline__ void stP(__hip_bfloat16* p, float v) { *p = __float2bfloat16(v); }

__device__ __forceinline__ void loadrow(const float* p, v4f& a, v4f& b) {
  a = ((const v4f*)p)[0];
  b = ((const v4f*)p)[1];
}
__device__ __forceinline__ void loadrow(const __hip_bfloat16* p, v4f& a, v4f& b) {
  const uint4 v = *(const uint4*)p;
  a = (v4f){ulo(v.x), uhi(v.x), ulo(v.y), uhi(v.y)};
  b = (v4f){ulo(v.z), uhi(v.z), ulo(v.w), uhi(v.w)};
}

__device__ __forceinline__ v2f fma2(v2f a, v2f b, v2f c) {
  return __builtin_elementwise_fma(a, b, c);
}
__device__ __forceinline__ float exp2_(float x) {
#if __has_builtin(__builtin_amdgcn_exp2f)
  return __builtin_amdgcn_exp2f(x);
#else
  return exp2f(x);
#endif
}

// ---- cross-lane XOR exchange, pure VALU DPP (16-lane rows) ----
template <int C>
__device__ __forceinline__ float dpp(float v) {
  return __int_as_float(__builtin_amdgcn_mov_dpp(__float_as_int(v), C, 0xF, 0xF, true));
}
__device__ __forceinline__ float xor4f(float v) { return dpp<0x1B>(dpp<0x141>(v)); }
__device__ __forceinline__ float xor8f(float v) { return dpp<0x128>(v); }

// One GRU cell update on a 16-lane cell. azr = (az,ar) partial with bias+x
// pre-seeded (z/r pre-scaled by log2e); ah partial pre-scaled by 2*log2e.
// w0..w3 = interleaved (whz,whr) for k=4hf+m; r0..r3 = wrh for k=4hf+m.
__device__ __forceinline__ float cell16(float hown, v2f azr, float ah,
                                        v2f w0, v2f w1, v2f w2, v2f w3,
                                        float r0, float r1, float r2, float r3,
                                        bool hfb) {
  const float x4 = xor4f(hown);
  const float v0 = hfb ? x4 : hown;
  const float v1 = dpp<0xB1>(v0), v2 = dpp<0x4E>(v0), v3 = dpp<0x1B>(v0);
  azr = fma2((v2f){v0, v0}, w0, azr);
  azr = fma2((v2f){v1, v1}, w1, azr);
  azr = fma2((v2f){v2, v2}, w2, azr);
  azr = fma2((v2f){v3, v3}, w3, azr);
  float az = azr.x, ar = azr.y;
  az += xor8f(az);  // combine halves
  ar += xor8f(ar);
  const float z = __builtin_amdgcn_rcpf(1.f + exp2_(-az));
  const float r = __builtin_amdgcn_rcpf(1.f + exp2_(-ar));
  const float hr = hown * r;
  const float y4 = xor4f(hr);
  const float u0 = hfb ? y4 : hr;
  const float u1 = dpp<0xB1>(u0), u2 = dpp<0x4E>(u0), u3 = dpp<0x1B>(u0);
  ah = fmaf(u0, r0, ah);
  ah = fmaf(u1, r1, ah);
  ah = fmaf(u2, r2, ah);
  ah = fmaf(u3, r3, ah);
  ah += xor8f(ah);
  ah = fmaxf(ah, -84.f);  // avoid inf -> NaN in tanh
  const float e = exp2_(-ah);
  const float Hc = (1.f - e) * __builtin_amdgcn_rcpf(1.f + e);
  return fmaf(z, Hc - hown, hown);
}

// ---------------------------------------------------------------------------
// Kernel 0: dtype probe (fp32 vs bf16 inputs).
// ---------------------------------------------------------------------------
__global__ void gru_detect(const unsigned short* __restrict__ u16, int* __restrict__ flag) {
  const int i = threadIdx.x;  // 64 threads
  float m = 0.f;
#pragma unroll
  for (int k = 0; k < 4; ++k) {
    const uint32_t u = u16[i * 4 + k];
    float v = fabsf(__uint_as_float(u << 16));
    if (!(v < 1e30f)) v = 1e30f;
    m = fmaxf(m, v);
  }
#pragma unroll
  for (int off = 32; off; off >>= 1) m = fmaxf(m, __shfl_down(m, off, 64));
  if (i == 0) *flag = (m > 2.0f) ? 0 : 1;  // 0 = fp32 inputs, 1 = bf16 inputs
}

// ---------------------------------------------------------------------------
// Kernel 1: layer-0 x-projections, stored pre-halved AND pre-scaled:
// z,r x 0.5*log2e; H x 0.5*2*log2e. Layout: pre[(b*S+t)*24 + j*3 + gate].
// ---------------------------------------------------------------------------
#define DECLP(p) v4f Za##p = {0,0,0,0}, Zb##p = {0,0,0,0}, Ra##p = {0,0,0,0}, \
                     Rb##p = {0,0,0,0}, Ha##p = {0,0,0,0}, Hb##p = {0,0,0,0}
#define FMAP(p, e) { Za##p += (e) * za; Zb##p += (e) * zb; Ra##p += (e) * ra; \
                     Rb##p += (e) * rb; Ha##p += (e) * ha; Hb##p += (e) * hb; }
#define SZR 0.72134752044448f  /* 0.5*log2e */
#define SH  1.44269504088896f  /* 0.5*2*log2e */
#define STOREP(p, pos) { PT* o = pre + (size_t)(pos) * 24;                       \
    stP(o+0,  SZR*Za##p[0]); stP(o+1,  SZR*Ra##p[0]); stP(o+2,  SH*Ha##p[0]);    \
    stP(o+3,  SZR*Za##p[1]); stP(o+4,  SZR*Ra##p[1]); stP(o+5,  SH*Ha##p[1]);    \
    stP(o+6,  SZR*Za##p[2]); stP(o+7,  SZR*Ra##p[2]); stP(o+8,  SH*Ha##p[2]);    \
    stP(o+9,  SZR*Za##p[3]); stP(o+10, SZR*Ra##p[3]); stP(o+11, SH*Ha##p[3]);    \
    stP(o+12, SZR*Zb##p[0]); stP(o+13, SZR*Rb##p[0]); stP(o+14, SH*Hb##p[0]);    \
    stP(o+15, SZR*Zb##p[1]); stP(o+16, SZR*Rb##p[1]); stP(o+17, SH*Hb##p[1]);    \
    stP(o+18, SZR*Zb##p[2]); stP(o+19, SZR*Rb##p[2]); stP(o+20, SH*Hb##p[2]);    \
    stP(o+21, SZR*Zb##p[3]); stP(o+22, SZR*Rb##p[3]); stP(o+23, SH*Hb##p[3]); }

template <typename T, typename PT>
__device__ void pre_body(const Args& a) {
  const int* x = (const int*)a.x;
  const T* emb = (const T*)a.emb;
  const T* Wz = (const T*)a.Wxz0;
  const T* Wr = (const T*)a.Wxr0;
  const T* Wh = (const T*)a.WxH0;
  PT* pre = (PT*)a.pre;

  const int pos0 = (blockIdx.x * 256 + threadIdx.x) * 4;  // 4 tokens/thread
  const int4 t4 = *(const int4*)(x + pos0);

  DECLP(0); DECLP(1); DECLP(2); DECLP(3);

  for (int kb = 0; kb < 8; ++kb) {
    v4f eA0, eB0, eA1, eB1, eA2, eB2, eA3, eB3;
    loadrow(emb + (size_t)t4.x * E_ + kb * 8, eA0, eB0);
    loadrow(emb + (size_t)t4.y * E_ + kb * 8, eA1, eB1);
    loadrow(emb + (size_t)t4.z * E_ + kb * 8, eA2, eB2);
    loadrow(emb + (size_t)t4.w * E_ + kb * 8, eA3, eB3);
#pragma unroll
    for (int k8 = 0; k8 < 8; ++k8) {
      v4f za, zb, ra, rb, ha, hb;
      const int row = (kb * 8 + k8) * 8;  // wave-uniform
      loadrow(Wz + row, za, zb);
      loadrow(Wr + row, ra, rb);
      loadrow(Wh + row, ha, hb);
      const float e0 = (k8 < 4) ? eA0[k8 & 3] : eB0[k8 & 3];
      const float e1 = (k8 < 4) ? eA1[k8 & 3] : eB1[k8 & 3];
      const float e2 = (k8 < 4) ? eA2[k8 & 3] : eB2[k8 & 3];
      const float e3 = (k8 < 4) ? eA3[k8 & 3] : eB3[k8 & 3];
      FMAP(0, e0); FMAP(1, e1); FMAP(2, e2); FMAP(3, e3);
    }
  }
  STOREP(0, pos0 + 0); STOREP(1, pos0 + 1);
  STOREP(2, pos0 + 2); STOREP(3, pos0 + 3);
}

template <typename PT>
__global__ __launch_bounds__(256, 2) void gru_pre_k(Args a) {
  if (*a.flag == 0) pre_body<float, PT>(a);
  else pre_body<__hip_bfloat16, PT>(a);
}

// ---------------------------------------------------------------------------
// Kernel 2: pipelined recurrence. 16 lanes/cell (lane = hf*8+j; half hf owns
// k in {4hf..4hf+3}). All h exchange via DPP; packed (z,r) fp32 math; LDS
// only for the inter-layer x handoff. No pins, no arrays.
// ---------------------------------------------------------------------------
template <typename T, typename PT>
__device__ void rec_body(const Args& a, float* xbuf) {
  const PT* pre = (const PT*)a.pre;
  const T* Whz0 = (const T*)a.Whz0; const T* bz0 = (const T*)a.bz0;
  const T* Whr0 = (const T*)a.Whr0; const T* br0 = (const T*)a.br0;
  const T* WrH0 = (const T*)a.WrH0; const T* bH0 = (const T*)a.bH0;
  const T* Wxz = (const T*)a.Wxz; const T* Whz = (const T*)a.Whz;
  const T* bz = (const T*)a.bz; const T* Wxr = (const T*)a.Wxr;
  const T* Whr = (const T*)a.Whr; const T* br = (const T*)a.br;
  const T* WxH = (const T*)a.WxH; const T* WrH = (const T*)a.WrH;
  const T* bH = (const T*)a.bH; const T* Why = (const T*)a.Why;
  const T* by = (const T*)a.by;
  T* out = (T*)a.out;

  const int tid = threadIdx.x;
  const int cell = tid >> 4;      // == layer l (1 batch elem per block)
  const int hf = (tid >> 3) & 1;
  const int j = tid & 7;
  const int l = cell;
  const int b = blockIdx.x;
  const bool hfb = (hf != 0);

  // ---- weights as named SSA values (no arrays, no pins) ----
  v2f wxzr0 = {0,0}, wxzr1 = {0,0}, wxzr2 = {0,0}, wxzr3 = {0,0};  // (Wxz,Wxr)*KZR
  float wxh0 = 0.f, wxh1 = 0.f, wxh2 = 0.f, wxh3 = 0.f;            // WxH*KH
  v2f whzr0, whzr1, whzr2, whzr3;                                  // (Whz,Whr)*KZR
  float wrh0, wrh1, wrh2, wrh3;                                    // WrH*KH
  v2f bzr; float bh;
  if (l == 0) {
#define LD0(m) { const int rk = (j ^ (4 * hf + m)) * 8 + j;                     \
      whzr##m = (v2f){KZR * toF(Whz0[rk]), KZR * toF(Whr0[rk])};                \
      wrh##m = KH * toF(WrH0[rk]); }
    LD0(0) LD0(1) LD0(2) LD0(3)
#undef LD0
    bzr = (v2f){0.5f * KZR * toF(bz0[j]), 0.5f * KZR * toF(br0[j])};
    bh = 0.5f * KH * toF(bH0[j]);
  } else {
    const int base = (l - 1) * 64;
#define LDN(m) { const int km = 4 * hf + m;                                     \
      const int nk = base + km * 8 + j;                                         \
      const int rk = base + (j ^ km) * 8 + j;                                   \
      wxzr##m = (v2f){KZR * toF(Wxz[nk]), KZR * toF(Wxr[nk])};                  \
      wxh##m = KH * toF(WxH[nk]);                                               \
      whzr##m = (v2f){KZR * toF(Whz[rk]), KZR * toF(Whr[rk])};                  \
      wrh##m = KH * toF(WrH[rk]); }
    LDN(0) LDN(1) LDN(2) LDN(3)
#undef LDN
    bzr = (v2f){0.5f * KZR * toF(bz[(l - 1) * 8 + j]),
                0.5f * KZR * toF(br[(l - 1) * 8 + j])};
    bh = 0.5f * KH * toF(bH[(l - 1) * 8 + j]);
  }

  // layer-0 precomputed x-projection (pre-halved & pre-scaled)
  const PT* ppr = pre + (size_t)b * (S_ * 24) + j * 3;
  float cz0 = 0.f, cr0 = 0.f, ch0 = 0.f, cz1 = 0.f, cr1 = 0.f, ch1 = 0.f;
  if (l == 0) {
    cz0 = toF(ppr[0]);  cr0 = toF(ppr[1]);  ch0 = toF(ppr[2]);
    cz1 = toF(ppr[24]); cr1 = toF(ppr[25]); ch1 = toF(ppr[26]);
  }

  const int gp = (cell > 0) ? (cell - 1) * XG : 0;
  const float* xpe = xbuf + NCELL * XG + gp + hf * 4;  // read when s even
  const float* xpo = xbuf + gp + hf * 4;               // read when s odd
  float* xce = xbuf + cell * XG;                       // write when s even
  float* xco = xbuf + NCELL * XG + cell * XG;          // write when s odd

  float hown = 0.f;  // h[j], replicated in both halves
  __syncthreads();

  for (int s = 0; s < NSUPER; ++s) {
    const unsigned rel = (unsigned)(s - l);
    if (rel < (unsigned)(S_ / 2)) {
      const float* xp = (s & 1) ? xpo : xpe;
      float* xc = (s & 1) ? xco : xce;
      v2f azr0 = bzr, azr1 = bzr;
      float ah0 = bh, ah1 = bh;
      if (l == 0) {
        azr0 += (v2f){cz0, cr0}; ah0 += ch0;
        azr1 += (v2f){cz1, cr1}; ah1 += ch1;
        if (rel + 1 < (unsigned)(S_ / 2)) {  // prefetch next superstep
          const PT* pn = ppr + (size_t)(rel + 1) * 48;
          cz0 = toF(pn[0]);  cr0 = toF(pn[1]);  ch0 = toF(pn[2]);
          cz1 = toF(pn[24]); cr1 = toF(pn[25]); ch1 = toF(pn[26]);
        }
      } else {
        const v4f x0 = *(const v4f*)(xp);      // slot0, my k-half
        const v4f x1 = *(const v4f*)(xp + 8);  // slot1, my k-half
        azr0 = fma2((v2f){x0.x, x0.x}, wxzr0, azr0); ah0 = fmaf(x0.x, wxh0, ah0);
        azr0 = fma2((v2f){x0.y, x0.y}, wxzr1, azr0); ah0 = fmaf(x0.y, wxh1, ah0);
        azr0 = fma2((v2f){x0.z, x0.z}, wxzr2, azr0); ah0 = fmaf(x0.z, wxh2, ah0);
        azr0 = fma2((v2f){x0.w, x0.w}, wxzr3, azr0); ah0 = fmaf(x0.w, wxh3, ah0);
        azr1 = fma2((v2f){x1.x, x1.x}, wxzr0, azr1); ah1 = fmaf(x1.x, wxh0, ah1);
        azr1 = fma2((v2f){x1.y, x1.y}, wxzr1, azr1); ah1 = fmaf(x1.y, wxh1, ah1);
        azr1 = fma2((v2f){x1.z, x1.z}, wxzr2, azr1); ah1 = fmaf(x1.z, wxh2, ah1);
        azr1 = fma2((v2f){x1.w, x1.w}, wxzr3, azr1); ah1 = fmaf(x1.w, wxh3, ah1);
      }
      const float hn0 = cell16(hown, azr0, ah0, whzr0, whzr1, whzr2, whzr3,
                               wrh0, wrh1, wrh2, wrh3, hfb);
      const float hn1 = cell16(hn0, azr1, ah1, whzr0, whzr1, whzr2, whzr3,
                               wrh0, wrh1, wrh2, wrh3, hfb);
      xc[j] = hn0;      // both halves write identical values (benign dup)
      xc[8 + j] = hn1;
      hown = hn1;
    }
    __syncthreads();
  }

  // ---- epilogue: h_last (dup-write benign) and logits ----
  stP(out + B_ + (l * B_ + b) * 8 + j, hown);
  if (l == L_ - 1) {
    float sum = hown * toF(Why[j]);
    sum += dpp<0xB1>(sum);
    sum += dpp<0x4E>(sum);
    sum += xor4f(sum);
    if (j == 0) stP(out + b, sum + toF(by[0]));
  }
}

template <typename PT>
__global__ __launch_bounds__(TPBR, 4) void gru_rec_k(Args a) {
  __shared__ __align__(16) float xbuf[2 * NCELL * XG];
  if (*a.flag == 0) rec_body<float, PT>(a, xbuf);
  else rec_body<__hip_bfloat16, PT>(a, xbuf);
}

// ---------------------------------------------------------------------------
extern "C" void kernel_launch(void* const* d_in, const int* in_sizes, int n_in,
                              void* d_out, int out_size, void* d_ws, size_t ws_size,
                              hipStream_t stream) {
  Args a;
  a.x = d_in[0];  a.emb = d_in[1];
  a.Wxz0 = d_in[2]; a.Whz0 = d_in[3]; a.bz0 = d_in[4];
  a.Wxr0 = d_in[5]; a.Whr0 = d_in[6]; a.br0 = d_in[7];
  a.WxH0 = d_in[8]; a.WrH0 = d_in[9]; a.bH0 = d_in[10];
  a.Wxz = d_in[11]; a.Whz = d_in[12]; a.bz = d_in[13];
  a.Wxr = d_in[14]; a.Whr = d_in[15]; a.br = d_in[16];
  a.WxH = d_in[17]; a.WrH = d_in[18]; a.bH = d_in[19];
  a.Why = d_in[20]; a.by = d_in[21];
  a.out = d_out;
  a.flag = (const int*)d_ws;
  a.pre = (char*)d_ws + 256;

  gru_detect<<<1, 64, 0, stream>>>((const unsigned short*)d_in[1], (int*)d_ws);

  const size_t needF = (size_t)B_ * S_ * 24 * sizeof(float) + 256;
  const int preGrid = B_ * S_ / 4 / 256;  // 500
  if (ws_size >= needF) {
    gru_pre_k<float><<<preGrid, 256, 0, stream>>>(a);
    gru_rec_k<float><<<B_, TPBR, 0, stream>>>(a);
  } else {  // small workspace: bf16 pre buffer
    gru_pre_k<__hip_bfloat16><<<preGrid, 256, 0, stream>>>(a);
    gru_rec_k<__hip_bfloat16><<<B_, TPBR, 0, stream>>>(a);
  }
}